// Round 3
// 115.459 us; speedup vs baseline: 1.0069x; 1.0069x over previous
//
#include <hip/hip_runtime.h>
#include <math.h>

#define L2C  1e-4
#define SIGC 0.1
#define NITER 20

// gfx950 permlane swaps via BUILTINS (not inline asm).
// R0 lesson: `b=a; asm(...%0,%1..."+v"(a),"+v"(b))` can coalesce a,b into one
// physreg -> swap-with-self -> both outputs x[l^m] -> 2*x[l^m] butterfly -> NaN.
// R1 lesson: materializing the copy INSIDE asm trips the CDNA VALU-write ->
// permlane-read hazard (compiler can't insert wait states inside an asm blob)
// -> stale register read -> NaN. The intrinsic form fixes both: two distinct
// SSA results (distinct physregs guaranteed) and compiler-managed hazard nops.
// Fallback: the harness-proven __shfl_xor (ds_bpermute) path.
#if defined(__has_builtin)
#  if __has_builtin(__builtin_amdgcn_permlane16_swap) && __has_builtin(__builtin_amdgcn_permlane32_swap)
#    define HAVE_PLSWAP 1
#  endif
#endif
#ifndef HAVE_PLSWAP
#  define HAVE_PLSWAP 0
#endif

// ---- cross-lane helpers ----------------------------------------------------
__device__ __forceinline__ double rld(double v, int lane) {
    union { double d; int i[2]; } u, r; u.d = v;
    r.i[0] = __builtin_amdgcn_readlane(u.i[0], lane);
    r.i[1] = __builtin_amdgcn_readlane(u.i[1], lane);
    return r.d;
}
template <int CTRL>
__device__ __forceinline__ double dppd(double v) {
    union { double d; int i[2]; } u, r; u.d = v;
    r.i[0] = __builtin_amdgcn_update_dpp(0, u.i[0], CTRL, 0xF, 0xF, true);
    r.i[1] = __builtin_amdgcn_update_dpp(0, u.i[1], CTRL, 0xF, 0xF, true);
    return r.d;
}
// sum across each 16-lane DPP row (all lanes get the row total)
__device__ __forceinline__ double sum16d(double v) {
    v += dppd<0xB1>(v); v += dppd<0x4E>(v); v += dppd<0x124>(v); v += dppd<0x128>(v);
    return v;
}
template <int CTRL>
__device__ __forceinline__ float dppf(float v) {
    return __int_as_float(__builtin_amdgcn_update_dpp(0, __float_as_int(v), CTRL, 0xF, 0xF, true));
}
__device__ __forceinline__ float min16f(float v) {
    v = fminf(v, dppf<0xB1>(v)); v = fminf(v, dppf<0x4E>(v));
    v = fminf(v, dppf<0x124>(v)); v = fminf(v, dppf<0x128>(v));
    return v;
}
__device__ __forceinline__ double mkd(unsigned lo, unsigned hi) {
    union { unsigned u[2]; double d; } r; r.u[0] = lo; r.u[1] = hi; return r.d;
}
__device__ __forceinline__ void dsplit(double v, unsigned &lo, unsigned &hi) {
    union { double d; unsigned u[2]; } x; x.d = v; lo = x.u[0]; hi = x.u[1];
}
// combine the 4 16-lane rows (sum; all lanes get the 64-lane-total of their
// q-position group {q, q+16, q+32, q+48}).
// NOTE: with both intrinsic inputs = x, the result pair is {x[l&~m], x[l|m]}
// in SOME order (pairwise swap within {l, l^m}); + and fmin are commutative,
// so sums/mins are correct under either convention — numerically identical
// (bitwise) to the __shfl_xor baseline.
__device__ __forceinline__ double cross4d(double v) {
#if HAVE_PLSWAP
    unsigned lo, hi; dsplit(v, lo, hi);
    auto rl = __builtin_amdgcn_permlane16_swap(lo, lo, false, false);
    auto rh = __builtin_amdgcn_permlane16_swap(hi, hi, false, false);
    v = mkd(rl[0], rh[0]) + mkd(rl[1], rh[1]);
    dsplit(v, lo, hi);
    auto sl = __builtin_amdgcn_permlane32_swap(lo, lo, false, false);
    auto sh = __builtin_amdgcn_permlane32_swap(hi, hi, false, false);
    return mkd(sl[0], sh[0]) + mkd(sl[1], sh[1]);
#else
    v += __shfl_xor(v, 16, 64); v += __shfl_xor(v, 32, 64); return v;
#endif
}
__device__ __forceinline__ float cross4minf(float v) {
#if HAVE_PLSWAP
    auto a = __builtin_amdgcn_permlane16_swap(__float_as_uint(v), __float_as_uint(v), false, false);
    v = fminf(__uint_as_float(a[0]), __uint_as_float(a[1]));
    auto b = __builtin_amdgcn_permlane32_swap(__float_as_uint(v), __float_as_uint(v), false, false);
    return fminf(__uint_as_float(b[0]), __uint_as_float(b[1]));
#else
    v = fminf(v, __shfl_xor(v, 16, 64)); v = fminf(v, __shfl_xor(v, 32, 64)); return v;
#endif
}
// fast fp64 reciprocal: fp32 seed + one fp64 Newton (~1e-14 rel err)
__device__ __forceinline__ double drcp(double d) {
    double x = (double)__builtin_amdgcn_rcpf((float)d);
    x = x * (2.0 - d * x);
    return x;
}
__device__ __forceinline__ float frcpf(float x) { return __builtin_amdgcn_rcpf(x); }

// One 64-lane wave per batch element. Lane l: q=l&15 (flow row q), r=l>>4;
// owns cells (q, 4c+r), c=0..3. fp64 state, fixed sigma=0.1, separate
// primal/dual step lengths, exit at mu<1e-4 (the harness-proven numerics).
// Latency-bound (1 wave/SIMD): xor16/xor32 butterflies on permlane-swap
// builtins (VALU) instead of ds_bpermute; Qst LDS round-trip replaced by
// direct __shfl; pivot floors precomputed off the LDLT serial chain; rcps +
// invDl stores hoisted above the mu reduce. Schur staging stays on LDS
// (convention-sensitive permlane gather deferred until swaps are proven).
__global__ __launch_bounds__(64, 1) void emd_ip_kernel(const float* __restrict__ jets1,
                                                       const float* __restrict__ jets2,
                                                       float* __restrict__ out) {
    const int l = threadIdx.x;
    const int b = blockIdx.x;
    const int q = l & 15;
    const int r = l >> 4;

    __shared__ double invDl[16 * 17];      // C[i][j] at i*17+j (stride-17: conflict-free)
    __shared__ double Sst[16 * 17];        // Schur staging
    __shared__ double Lst[16 * 17];        // Lst[a*17+b] = L[b][a] (unit-diag L)
    __shared__ double GstR[16], GstI[16];  // rhs staging

    const float* p1 = jets1 + b * 48;
    const float* p2 = jets2 + b * 48;

    double ax = (double)p1[3 * q], ay = (double)p1[3 * q + 1];
    double px[4];
#pragma unroll
    for (int c = 0; c < 4; c++) {
        int j = 4 * c + r;
        double d0 = ((double)p2[3 * j]     - ax) + 1e-12;
        double d1 = ((double)p2[3 * j + 1] - ay) + 1e-12;
        px[c] = sqrt(d0 * d0 + d1 * d1);
    }
    double h_rt = (double)p1[3 * q + 2];
    double h_ct[4];
#pragma unroll
    for (int c = 0; c < 4; c++) h_ct[c] = (double)p2[3 * (4 * c + r) + 2];

    double sw1 = sum16d(h_rt);
    double sw2 = sum16d((double)p2[3 * q + 2]);
    const double sB = fmin(sw1, sw2);
    const double sE = fabs(sw1 - sw2);

    double x[4] = {0, 0, 0, 0}, s[4] = {1, 1, 1, 1}, z[4] = {1, 1, 1, 1};
    double yv = 0.0;
    double s_rt = 1.0, z_rt = 1.0;
    double s_ct[4] = {1, 1, 1, 1}, z_ct[4] = {1, 1, 1, 1};
    // incrementally-maintained sums of x (x starts at 0)
    double rsx = 0.0;                      // row-q sum of x
    double cs[4] = {0, 0, 0, 0};           // col 4c+r sums of x
    double ra = -sB;                       // sum(x) - sB

    for (int it = 0; it < NITER; ++it) {
        // ---- hoisted reciprocal chains + invDl stores (mu-independent; they
        //      overlap the mu butterfly and bury the invDl lgkm latency) ----
        double is_rt = drcp(s_rt);
        double is_ct[4];
#pragma unroll
        for (int c = 0; c < 4; c++) is_ct[c] = drcp(s_ct[c]);
        double is_[4], iD[4];
#pragma unroll
        for (int c = 0; c < 4; c++) {
            is_[c] = drcp(s[c]);
            iD[c] = drcp(L2C + z[c] * is_[c]);
            invDl[q * 17 + 4 * c + r] = iD[c];
        }

        // ---- mu = mean(s*z) over 288 (redundant copies scaled) ----
        double mub = s[0]*z[0] + s[1]*z[1] + s[2]*z[2] + s[3]*z[3]
                   + 0.25 * (s_rt * z_rt)
                   + 0.0625 * (s_ct[0]*z_ct[0] + s_ct[1]*z_ct[1] + s_ct[2]*z_ct[2] + s_ct[3]*z_ct[3]);
        double mu = sum16d(cross4d(mub)) * (1.0 / 288.0);
        if (!(mu >= 1e-4)) break;   // gap ~ 288*mu ~ 2.9e-2 < 9.6e-2/2; catches NaN
        double sgmu = SIGC * mu;

        // ---- tail residuals (lane-local; rsx/cs maintained incrementally) ----
        double rp_rt = rsx + s_rt - h_rt;
        double rs_rt = s_rt * z_rt - sgmu;
        double tt_rt = (z_rt * (rsx - h_rt) + sgmu) * is_rt;
        double rp_ct[4], rs_ct[4], tt_ct[4];
#pragma unroll
        for (int c = 0; c < 4; c++) {
            rp_ct[c] = cs[c] + s_ct[c] - h_ct[c];
            rs_ct[c] = s_ct[c] * z_ct[c] - sgmu;
            tt_ct[c] = (z_ct[c] * (cs[c] - h_ct[c]) + sgmu) * is_ct[c];
        }

        // ---- cell residuals ----
        double rp[4], rs[4], r1[4], rD1[4];
#pragma unroll
        for (int c = 0; c < 4; c++) {
            double rx = L2C * x[c] + px[c] + (-z[c] + z_rt + z_ct[c]) + yv;
            rp[c] = s[c] - x[c];
            rs[c] = s[c] * z[c] - sgmu;
            double tk = (sgmu - z[c] * x[c]) * is_[c];   // (z*rp - rs)/s
            r1[c] = rx - tk + tt_rt + tt_ct[c];
            rD1[c] = r1[c] * iD[c];
        }

        // ---- sums of invD, rD1 ----
        double rsI = cross4d(iD[0] + iD[1] + iD[2] + iD[3]);
        double rsR = cross4d(rD1[0] + rD1[1] + rD1[2] + rD1[3]);
        double csI[4], csR[4];
#pragma unroll
        for (int c = 0; c < 4; c++) { csI[c] = sum16d(iD[c]); csR[c] = sum16d(rD1[c]); }

        double ar = drcp(s_rt * drcp(z_rt) + rsI);   // 1/A_q
        double aR = ar * rsR;
        double aI = ar * rsI;

        // ---- rhs gp[j] = g_c[j] - sum_i aX_i*C[i][j] (DPP row reduction) ----
        double gpR[4], gpI[4], bb[4];
#pragma unroll
        for (int c = 0; c < 4; c++) {
            gpR[c] = csR[c] - sum16d(aR * iD[c]);
            gpI[c] = csI[c] - sum16d(aI * iD[c]);
            bb[c]  = s_ct[c] * drcp(z_ct[c]) + csI[c];
            if (q == 4 * c + r) { GstR[q] = gpR[c]; GstI[q] = gpI[c]; }  // stage
        }

        // ---- Schur S[q][4c+r] = diag - sum_t ar_t C[t][q] C[t][4c+r] ----
        double accS[4] = {0, 0, 0, 0};
#pragma unroll
        for (int t = 0; t < 16; t++) {
            double w = rld(ar, t) * invDl[t * 17 + q];
#pragma unroll
            for (int c = 0; c < 4; c++) accS[c] += w * invDl[t * 17 + 4 * c + r];
        }
#pragma unroll
        for (int c = 0; c < 4; c++)
            Sst[q * 17 + 4 * c + r] = ((q == 4 * c + r) ? bb[c] : 0.0) - accS[c];

        // ---- load S row q from LDS ----
        double Sr[16];
#pragma unroll
        for (int j2 = 0; j2 < 16; j2++) Sr[j2] = Sst[q * 17 + j2];

        // ---- pivot floors precomputed (off the serial pivot chain) ----
        double flo[16];
#pragma unroll
        for (int kk = 0; kk < 16; kk++)
            flo[kk] = fmax(1e-12 * fabs(rld(Sr[kk], kk)), 1e-280);

        // ---- 16x16 LDLT in registers (unit-diag L); columns staged to LDS ----
        double invdv = 0.0;   // 1/d_q (own pivot) for the D-divide
#pragma unroll
        for (int kk = 0; kk < 16; kk++) {
            double dkk = fmax(rld(Sr[kk], kk), flo[kk]);
            double inv = drcp(dkk);
            invdv = (q == kk) ? inv : invdv;
            double Lc = Sr[kk] * inv;      // L[q][kk] (unit diag; valid q>=kk)
            if (l < 16) Lst[kk * 17 + l] = Lc;
#pragma unroll
            for (int jj = kk + 1; jj < 16; jj++)
                Sr[jj] -= Sr[kk] * rld(Lc, jj);   // -= (L[q][kk]*d)*L[jj][kk]
            Sr[kk] = Lc;                   // keep L column for the forward solve
        }

        // ---- gather rhs + L^T row from LDS ----
        double y1 = GstR[q], y2 = GstI[q];
        double LTr[16];
#pragma unroll
        for (int kk = 0; kk < 16; kk++) LTr[kk] = Lst[q * 17 + kk];  // L[kk][q]

        // ---- forward solve L w = gp (unit L: no pivot scaling) ----
#pragma unroll
        for (int kk = 0; kk < 16; kk++) {
            double t1 = rld(y1, kk);
            double t2 = rld(y2, kk);
            if (q > kk) { y1 -= Sr[kk] * t1; y2 -= Sr[kk] * t2; }
        }
        // ---- D-divide (lane-local) ----
        y1 *= invdv;
        y2 *= invdv;
        // ---- backward solve L^T qc = v ----
#pragma unroll
        for (int kk = 15; kk >= 0; kk--) {
            double t1 = rld(y1, kk);
            double t2 = rld(y2, kk);
            if (q < kk) { y1 -= LTr[kk] * t1; y2 -= LTr[kk] * t2; }
        }
        // y1,y2 = qc[q] (identical across r-groups)

        // ---- gather qc per own columns (direct lane broadcast, no staging) ----
        double qc1c[4], qcvc[4];
#pragma unroll
        for (int c = 0; c < 4; c++) {
            qc1c[c] = __shfl(y1, 4 * c + r, 64);
            qcvc[c] = __shfl(y2, 4 * c + r, 64);
        }

        // ---- qr = ar*(g_r - sum_j C[q][j] qc_j) (cross4 reduction) ----
        double pr1 = iD[0]*qc1c[0] + iD[1]*qc1c[1] + iD[2]*qc1c[2] + iD[3]*qc1c[3];
        double prv = iD[0]*qcvc[0] + iD[1]*qcvc[1] + iD[2]*qcvc[2] + iD[3]*qcvc[3];
        double qr1 = ar * (rsR - cross4d(pr1));
        double qrv = ar * (rsI - cross4d(prv));

        // ---- u = H^{-1} r1, v = H^{-1} 1 ----
        double u[4], v[4];
#pragma unroll
        for (int c = 0; c < 4; c++) {
            u[c] = (r1[c] - qr1 - qc1c[c]) * iD[c];
            v[c] = (1.0  - qrv - qcvc[c]) * iD[c];
        }
        double usum = sum16d(cross4d(u[0] + u[1] + u[2] + u[3]));
        double vsum = sum16d(cross4d(v[0] + v[1] + v[2] + v[3]));
        double dy = (ra - usum) * drcp(vsum);

        // ---- dx + sums ----
        double dx[4];
#pragma unroll
        for (int c = 0; c < 4; c++) dx[c] = -u[c] - v[c] * dy;
        double rsdx = cross4d(dx[0] + dx[1] + dx[2] + dx[3]);
        double csdx[4];
#pragma unroll
        for (int c = 0; c < 4; c++) csdx[c] = sum16d(dx[c]);
        double sumdx = -usum - vsum * dy;   // sum over all cells of dx (exact identity)

        // ---- ds, dz; SEPARATE primal/dual ratio tests (fp32, 0.99 margin) ----
        float amP = 1e30f, amD = 1e30f;
        double ds[4], dz[4];
#pragma unroll
        for (int c = 0; c < 4; c++) {
            ds[c] = dx[c] - rp[c];
            dz[c] = -(rs[c] + z[c] * ds[c]) * is_[c];
            if (ds[c] < 0.0) amP = fminf(amP, (float)s[c] * frcpf((float)(-ds[c])));
            if (dz[c] < 0.0) amD = fminf(amD, (float)z[c] * frcpf((float)(-dz[c])));
        }
        double ds_rt = -rp_rt - rsdx;
        double dz_rt = -(rs_rt + z_rt * ds_rt) * is_rt;
        if (ds_rt < 0.0) amP = fminf(amP, (float)s_rt * frcpf((float)(-ds_rt)));
        if (dz_rt < 0.0) amD = fminf(amD, (float)z_rt * frcpf((float)(-dz_rt)));
        double ds_ct[4], dz_ct[4];
#pragma unroll
        for (int c = 0; c < 4; c++) {
            ds_ct[c] = -rp_ct[c] - csdx[c];
            dz_ct[c] = -(rs_ct[c] + z_ct[c] * ds_ct[c]) * is_ct[c];
            if (ds_ct[c] < 0.0) amP = fminf(amP, (float)s_ct[c] * frcpf((float)(-ds_ct[c])));
            if (dz_ct[c] < 0.0) amD = fminf(amD, (float)z_ct[c] * frcpf((float)(-dz_ct[c])));
        }
        float aPf = min16f(cross4minf(amP));
        float aDf = min16f(cross4minf(amD));
        double alphaP = 0.99 * fmin(1.0, (double)aPf);
        double alphaD = 0.99 * fmin(1.0, (double)aDf);
        bool good = ((dy - dy) == 0.0);   // freeze on garbage direction
        alphaP = good ? alphaP : 0.0;
        alphaD = good ? alphaD : 0.0;

        // ---- step (x,s with alphaP; z,y with alphaD; x-sums incremental) ----
#pragma unroll
        for (int c = 0; c < 4; c++) {
            x[c] += alphaP * dx[c];
            s[c] += alphaP * ds[c];
            z[c] += alphaD * dz[c];
            s_ct[c] += alphaP * ds_ct[c];
            z_ct[c] += alphaD * dz_ct[c];
            cs[c] += alphaP * csdx[c];
        }
        yv += alphaD * dy;
        s_rt += alphaP * ds_rt;
        z_rt += alphaD * dz_rt;
        rsx += alphaP * rsdx;
        ra  += alphaP * sumdx;
    }

    // ---- emd = p.x + |sum w1 - sum w2| ----
    double e = sum16d(cross4d(px[0]*x[0] + px[1]*x[1] + px[2]*x[2] + px[3]*x[3]));
    if (l == 0) out[b] = (float)(e + sE);
}

extern "C" void kernel_launch(void* const* d_in, const int* in_sizes, int n_in,
                              void* d_out, int out_size, void* d_ws, size_t ws_size,
                              hipStream_t stream) {
    const float* jets1 = (const float*)d_in[0];
    const float* jets2 = (const float*)d_in[1];
    float* out = (float*)d_out;
    int B = in_sizes[0] / 48;   // 32
    emd_ip_kernel<<<dim3(B), dim3(64), 0, stream>>>(jets1, jets2, out);
}

// Round 4
// 112.956 us; speedup vs baseline: 1.0292x; 1.0222x over previous
//
#include <hip/hip_runtime.h>
#include <math.h>

#define L2C  1e-4
#define SIGC 0.1
#define NITER 20

// permlane swaps via builtins (R2-proven green; R0/R1 asm variants NaN'd:
// regalloc coalescing + unhandled VALU->permlane hazard inside asm blobs).
#if defined(__has_builtin)
#  if __has_builtin(__builtin_amdgcn_permlane16_swap) && __has_builtin(__builtin_amdgcn_permlane32_swap)
#    define HAVE_PLSWAP 1
#  endif
#  if __has_builtin(__builtin_amdgcn_rcp)
#    define HAVE_RCP64 1
#  endif
#endif
#ifndef HAVE_PLSWAP
#  define HAVE_PLSWAP 0
#endif
#ifndef HAVE_RCP64
#  define HAVE_RCP64 0
#endif

// ---- cross-lane helpers ----------------------------------------------------
__device__ __forceinline__ double rld(double v, int lane) {
    union { double d; int i[2]; } u, r; u.d = v;
    r.i[0] = __builtin_amdgcn_readlane(u.i[0], lane);
    r.i[1] = __builtin_amdgcn_readlane(u.i[1], lane);
    return r.d;
}
template <int CTRL>
__device__ __forceinline__ double dppd(double v) {
    union { double d; int i[2]; } u, r; u.d = v;
    r.i[0] = __builtin_amdgcn_update_dpp(0, u.i[0], CTRL, 0xF, 0xF, true);
    r.i[1] = __builtin_amdgcn_update_dpp(0, u.i[1], CTRL, 0xF, 0xF, true);
    return r.d;
}
// sum across each 16-lane DPP row (all lanes get the row total)
__device__ __forceinline__ double sum16d(double v) {
    v += dppd<0xB1>(v); v += dppd<0x4E>(v); v += dppd<0x124>(v); v += dppd<0x128>(v);
    return v;
}
template <int CTRL>
__device__ __forceinline__ float dppf(float v) {
    return __int_as_float(__builtin_amdgcn_update_dpp(0, __float_as_int(v), CTRL, 0xF, 0xF, true));
}
__device__ __forceinline__ float min16f(float v) {
    v = fminf(v, dppf<0xB1>(v)); v = fminf(v, dppf<0x4E>(v));
    v = fminf(v, dppf<0x124>(v)); v = fminf(v, dppf<0x128>(v));
    return v;
}
__device__ __forceinline__ double mkd(unsigned lo, unsigned hi) {
    union { unsigned u[2]; double d; } r; r.u[0] = lo; r.u[1] = hi; return r.d;
}
__device__ __forceinline__ void dsplit(double v, unsigned &lo, unsigned &hi) {
    union { double d; unsigned u[2]; } x; x.d = v; lo = x.u[0]; hi = x.u[1];
}
// combine the 4 16-lane rows (sum over {q, q+16, q+32, q+48}); order-independent.
__device__ __forceinline__ double cross4d(double v) {
#if HAVE_PLSWAP
    unsigned lo, hi; dsplit(v, lo, hi);
    auto rl = __builtin_amdgcn_permlane16_swap(lo, lo, false, false);
    auto rh = __builtin_amdgcn_permlane16_swap(hi, hi, false, false);
    v = mkd(rl[0], rh[0]) + mkd(rl[1], rh[1]);
    dsplit(v, lo, hi);
    auto sl = __builtin_amdgcn_permlane32_swap(lo, lo, false, false);
    auto sh = __builtin_amdgcn_permlane32_swap(hi, hi, false, false);
    return mkd(sl[0], sh[0]) + mkd(sl[1], sh[1]);
#else
    v += __shfl_xor(v, 16, 64); v += __shfl_xor(v, 32, 64); return v;
#endif
}
__device__ __forceinline__ float cross4minf(float v) {
#if HAVE_PLSWAP
    auto a = __builtin_amdgcn_permlane16_swap(__float_as_uint(v), __float_as_uint(v), false, false);
    v = fminf(__uint_as_float(a[0]), __uint_as_float(a[1]));
    auto b = __builtin_amdgcn_permlane32_swap(__float_as_uint(v), __float_as_uint(v), false, false);
    return fminf(__uint_as_float(b[0]), __uint_as_float(b[1]));
#else
    v = fminf(v, __shfl_xor(v, 16, 64)); v = fminf(v, __shfl_xor(v, 32, 64)); return v;
#endif
}
// fast fp64 reciprocal, ~1e-14 rel err.
// R3: seed with v_rcp_f64 when available (kills 2 f64<->f32 converts per rcp:
// shorter dependent chain AND fewer issue slots; ~20 drcps/iter, 16 of them on
// the LDLT pivot ladder). Seed accuracy >= fp32 seed, so one Newton suffices
// either way; numerics equal-or-better than the proven baseline.
__device__ __forceinline__ double drcp(double d) {
#if HAVE_RCP64
    double x = __builtin_amdgcn_rcp(d);
#else
    double x = (double)__builtin_amdgcn_rcpf((float)d);
#endif
    x = x * (2.0 - d * x);
    return x;
}
__device__ __forceinline__ float frcpf(float x) { return __builtin_amdgcn_rcpf(x); }

// One 64-lane wave per batch element. Lane l: q=l&15 (flow row q), r=l>>4;
// owns cells (q, 4c+r), c=0..3. fp64 state, fixed sigma=0.1, separate
// primal/dual step lengths, exit at mu<1e-4 (the harness-proven numerics).
// Profile model (R2): ~52% of the active SIMD's issue slots busy -> half
// issue-bound (fp64 volume), half latency-bound (LDLT pivot ladder).
// R3 changes: v_rcp_f64-seeded drcp; pcand pivot bypass (next pivot readlane
// taken from a lane-local fma, bitwise-identical, one less broadcast per LDLT
// step); Schur accumulator split (chain depth 16->8); iz_rt/iz_ct hoisted and
// ar = drcp(srz + rsI) with srz precomputed off-chain.
__global__ __launch_bounds__(64, 1) void emd_ip_kernel(const float* __restrict__ jets1,
                                                       const float* __restrict__ jets2,
                                                       float* __restrict__ out) {
    const int l = threadIdx.x;
    const int b = blockIdx.x;
    const int q = l & 15;
    const int r = l >> 4;

    __shared__ double invDl[16 * 17];      // C[i][j] at i*17+j (stride-17: conflict-free)
    __shared__ double Sst[16 * 17];        // Schur staging
    __shared__ double Lst[16 * 17];        // Lst[a*17+b] = L[b][a] (unit-diag L)
    __shared__ double GstR[16], GstI[16];  // rhs staging

    const float* p1 = jets1 + b * 48;
    const float* p2 = jets2 + b * 48;

    double ax = (double)p1[3 * q], ay = (double)p1[3 * q + 1];
    double px[4];
#pragma unroll
    for (int c = 0; c < 4; c++) {
        int j = 4 * c + r;
        double d0 = ((double)p2[3 * j]     - ax) + 1e-12;
        double d1 = ((double)p2[3 * j + 1] - ay) + 1e-12;
        px[c] = sqrt(d0 * d0 + d1 * d1);
    }
    double h_rt = (double)p1[3 * q + 2];
    double h_ct[4];
#pragma unroll
    for (int c = 0; c < 4; c++) h_ct[c] = (double)p2[3 * (4 * c + r) + 2];

    double sw1 = sum16d(h_rt);
    double sw2 = sum16d((double)p2[3 * q + 2]);
    const double sB = fmin(sw1, sw2);
    const double sE = fabs(sw1 - sw2);

    double x[4] = {0, 0, 0, 0}, s[4] = {1, 1, 1, 1}, z[4] = {1, 1, 1, 1};
    double yv = 0.0;
    double s_rt = 1.0, z_rt = 1.0;
    double s_ct[4] = {1, 1, 1, 1}, z_ct[4] = {1, 1, 1, 1};
    // incrementally-maintained sums of x (x starts at 0)
    double rsx = 0.0;                      // row-q sum of x
    double cs[4] = {0, 0, 0, 0};           // col 4c+r sums of x
    double ra = -sB;                       // sum(x) - sB

    for (int it = 0; it < NITER; ++it) {
        // ---- hoisted reciprocal chains + invDl stores (mu-independent; they
        //      overlap the mu butterfly and bury the invDl lgkm latency) ----
        double is_rt = drcp(s_rt);
        double iz_rt = drcp(z_rt);
        double srz   = s_rt * iz_rt;           // s_rt/z_rt, off-chain
        double is_ct[4], iz_ct[4];
#pragma unroll
        for (int c = 0; c < 4; c++) { is_ct[c] = drcp(s_ct[c]); iz_ct[c] = drcp(z_ct[c]); }
        double is_[4], iD[4];
#pragma unroll
        for (int c = 0; c < 4; c++) {
            is_[c] = drcp(s[c]);
            iD[c] = drcp(L2C + z[c] * is_[c]);
            invDl[q * 17 + 4 * c + r] = iD[c];
        }

        // ---- mu = mean(s*z) over 288 (redundant copies scaled) ----
        double mub = s[0]*z[0] + s[1]*z[1] + s[2]*z[2] + s[3]*z[3]
                   + 0.25 * (s_rt * z_rt)
                   + 0.0625 * (s_ct[0]*z_ct[0] + s_ct[1]*z_ct[1] + s_ct[2]*z_ct[2] + s_ct[3]*z_ct[3]);
        double mu = sum16d(cross4d(mub)) * (1.0 / 288.0);
        if (!(mu >= 1e-4)) break;   // gap ~ 288*mu ~ 2.9e-2 < 9.6e-2/2; catches NaN
        double sgmu = SIGC * mu;

        // ---- tail residuals (lane-local; rsx/cs maintained incrementally) ----
        double rp_rt = rsx + s_rt - h_rt;
        double rs_rt = s_rt * z_rt - sgmu;
        double tt_rt = (z_rt * (rsx - h_rt) + sgmu) * is_rt;
        double rp_ct[4], rs_ct[4], tt_ct[4];
#pragma unroll
        for (int c = 0; c < 4; c++) {
            rp_ct[c] = cs[c] + s_ct[c] - h_ct[c];
            rs_ct[c] = s_ct[c] * z_ct[c] - sgmu;
            tt_ct[c] = (z_ct[c] * (cs[c] - h_ct[c]) + sgmu) * is_ct[c];
        }

        // ---- cell residuals ----
        double rp[4], rs[4], r1[4], rD1[4];
#pragma unroll
        for (int c = 0; c < 4; c++) {
            double rx = L2C * x[c] + px[c] + (-z[c] + z_rt + z_ct[c]) + yv;
            rp[c] = s[c] - x[c];
            rs[c] = s[c] * z[c] - sgmu;
            double tk = (sgmu - z[c] * x[c]) * is_[c];   // (z*rp - rs)/s
            r1[c] = rx - tk + tt_rt + tt_ct[c];
            rD1[c] = r1[c] * iD[c];
        }

        // ---- sums of invD, rD1 ----
        double rsI = cross4d(iD[0] + iD[1] + iD[2] + iD[3]);
        double rsR = cross4d(rD1[0] + rD1[1] + rD1[2] + rD1[3]);
        double csI[4], csR[4];
#pragma unroll
        for (int c = 0; c < 4; c++) { csI[c] = sum16d(iD[c]); csR[c] = sum16d(rD1[c]); }

        double ar = drcp(srz + rsI);   // 1/A_q (srz precomputed off-chain)
        double aR = ar * rsR;
        double aI = ar * rsI;

        // ---- rhs gp[j] = g_c[j] - sum_i aX_i*C[i][j] (DPP row reduction) ----
        double gpR[4], gpI[4], bb[4];
#pragma unroll
        for (int c = 0; c < 4; c++) {
            gpR[c] = csR[c] - sum16d(aR * iD[c]);
            gpI[c] = csI[c] - sum16d(aI * iD[c]);
            bb[c]  = s_ct[c] * iz_ct[c] + csI[c];
            if (q == 4 * c + r) { GstR[q] = gpR[c]; GstI[q] = gpI[c]; }  // stage
        }

        // ---- Schur S[q][4c+r] = diag - sum_t ar_t C[t][q] C[t][4c+r] ----
        // split accumulators: fp64 fma chain depth 16 -> 8 (+1 add)
        double accA[4] = {0, 0, 0, 0}, accB[4] = {0, 0, 0, 0};
#pragma unroll
        for (int t = 0; t < 8; t++) {
            double wA = rld(ar, t) * invDl[t * 17 + q];
            double wB = rld(ar, t + 8) * invDl[(t + 8) * 17 + q];
#pragma unroll
            for (int c = 0; c < 4; c++) {
                accA[c] += wA * invDl[t * 17 + 4 * c + r];
                accB[c] += wB * invDl[(t + 8) * 17 + 4 * c + r];
            }
        }
#pragma unroll
        for (int c = 0; c < 4; c++)
            Sst[q * 17 + 4 * c + r] = ((q == 4 * c + r) ? bb[c] : 0.0) - (accA[c] + accB[c]);

        // ---- load S row q from LDS ----
        double Sr[16];
#pragma unroll
        for (int j2 = 0; j2 < 16; j2++) Sr[j2] = Sst[q * 17 + j2];

        // ---- pivot floors precomputed (off the serial pivot chain) ----
        double flo[16];
#pragma unroll
        for (int kk = 0; kk < 16; kk++)
            flo[kk] = fmax(1e-12 * fabs(rld(Sr[kk], kk)), 1e-280);

        // ---- 16x16 LDLT in registers (unit-diag L); columns staged to LDS ----
        // pcand pivot bypass: lane kk+1's updated Sr[kk+1] equals the
        // lane-local fma Sr[kk+1] - Sr[kk]*Lc (its rld(Lc,kk+1) is its own Lc),
        // so the next pivot readlane comes off pcand — one fewer broadcast on
        // the serial ladder per step; bitwise-identical value.
        double invdv = 0.0;   // 1/d_q (own pivot) for the D-divide
        double pcand = 0.0;
#pragma unroll
        for (int kk = 0; kk < 16; kk++) {
            double praw = (kk == 0) ? rld(Sr[0], 0) : rld(pcand, kk);
            double dkk = fmax(praw, flo[kk]);
            double inv = drcp(dkk);
            invdv = (q == kk) ? inv : invdv;
            double Lc = Sr[kk] * inv;      // L[q][kk] (unit diag; valid q>=kk)
            if (l < 16) Lst[kk * 17 + l] = Lc;
            if (kk < 15) pcand = Sr[kk + 1] - Sr[kk] * Lc;   // lane-local next-pivot
#pragma unroll
            for (int jj = kk + 1; jj < 16; jj++)
                Sr[jj] -= Sr[kk] * rld(Lc, jj);   // -= (L[q][kk]*d)*L[jj][kk]
            Sr[kk] = Lc;                   // keep L column for the forward solve
        }

        // ---- gather rhs + L^T row from LDS ----
        double y1 = GstR[q], y2 = GstI[q];
        double LTr[16];
#pragma unroll
        for (int kk = 0; kk < 16; kk++) LTr[kk] = Lst[q * 17 + kk];  // L[kk][q]

        // ---- forward solve L w = gp (unit L: no pivot scaling) ----
#pragma unroll
        for (int kk = 0; kk < 16; kk++) {
            double t1 = rld(y1, kk);
            double t2 = rld(y2, kk);
            if (q > kk) { y1 -= Sr[kk] * t1; y2 -= Sr[kk] * t2; }
        }
        // ---- D-divide (lane-local) ----
        y1 *= invdv;
        y2 *= invdv;
        // ---- backward solve L^T qc = v ----
#pragma unroll
        for (int kk = 15; kk >= 0; kk--) {
            double t1 = rld(y1, kk);
            double t2 = rld(y2, kk);
            if (q < kk) { y1 -= LTr[kk] * t1; y2 -= LTr[kk] * t2; }
        }
        // y1,y2 = qc[q] (identical across r-groups)

        // ---- gather qc per own columns (direct lane broadcast, no staging) ----
        double qc1c[4], qcvc[4];
#pragma unroll
        for (int c = 0; c < 4; c++) {
            qc1c[c] = __shfl(y1, 4 * c + r, 64);
            qcvc[c] = __shfl(y2, 4 * c + r, 64);
        }

        // ---- qr = ar*(g_r - sum_j C[q][j] qc_j) (cross4 reduction) ----
        double pr1 = iD[0]*qc1c[0] + iD[1]*qc1c[1] + iD[2]*qc1c[2] + iD[3]*qc1c[3];
        double prv = iD[0]*qcvc[0] + iD[1]*qcvc[1] + iD[2]*qcvc[2] + iD[3]*qcvc[3];
        double qr1 = ar * (rsR - cross4d(pr1));
        double qrv = ar * (rsI - cross4d(prv));

        // ---- u = H^{-1} r1, v = H^{-1} 1 ----
        double u[4], v[4];
#pragma unroll
        for (int c = 0; c < 4; c++) {
            u[c] = (r1[c] - qr1 - qc1c[c]) * iD[c];
            v[c] = (1.0  - qrv - qcvc[c]) * iD[c];
        }
        double usum = sum16d(cross4d(u[0] + u[1] + u[2] + u[3]));
        double vsum = sum16d(cross4d(v[0] + v[1] + v[2] + v[3]));
        double dy = (ra - usum) * drcp(vsum);

        // ---- dx + sums ----
        double dx[4];
#pragma unroll
        for (int c = 0; c < 4; c++) dx[c] = -u[c] - v[c] * dy;
        double rsdx = cross4d(dx[0] + dx[1] + dx[2] + dx[3]);
        double csdx[4];
#pragma unroll
        for (int c = 0; c < 4; c++) csdx[c] = sum16d(dx[c]);
        double sumdx = -usum - vsum * dy;   // sum over all cells of dx (exact identity)

        // ---- ds, dz; SEPARATE primal/dual ratio tests (fp32, 0.99 margin) ----
        float amP = 1e30f, amD = 1e30f;
        double ds[4], dz[4];
#pragma unroll
        for (int c = 0; c < 4; c++) {
            ds[c] = dx[c] - rp[c];
            dz[c] = -(rs[c] + z[c] * ds[c]) * is_[c];
            if (ds[c] < 0.0) amP = fminf(amP, (float)s[c] * frcpf((float)(-ds[c])));
            if (dz[c] < 0.0) amD = fminf(amD, (float)z[c] * frcpf((float)(-dz[c])));
        }
        double ds_rt = -rp_rt - rsdx;
        double dz_rt = -(rs_rt + z_rt * ds_rt) * is_rt;
        if (ds_rt < 0.0) amP = fminf(amP, (float)s_rt * frcpf((float)(-ds_rt)));
        if (dz_rt < 0.0) amD = fminf(amD, (float)z_rt * frcpf((float)(-dz_rt)));
        double ds_ct[4], dz_ct[4];
#pragma unroll
        for (int c = 0; c < 4; c++) {
            ds_ct[c] = -rp_ct[c] - csdx[c];
            dz_ct[c] = -(rs_ct[c] + z_ct[c] * ds_ct[c]) * is_ct[c];
            if (ds_ct[c] < 0.0) amP = fminf(amP, (float)s_ct[c] * frcpf((float)(-ds_ct[c])));
            if (dz_ct[c] < 0.0) amD = fminf(amD, (float)z_ct[c] * frcpf((float)(-dz_ct[c])));
        }
        float aPf = min16f(cross4minf(amP));
        float aDf = min16f(cross4minf(amD));
        double alphaP = 0.99 * fmin(1.0, (double)aPf);
        double alphaD = 0.99 * fmin(1.0, (double)aDf);
        bool good = ((dy - dy) == 0.0);   // freeze on garbage direction
        alphaP = good ? alphaP : 0.0;
        alphaD = good ? alphaD : 0.0;

        // ---- step (x,s with alphaP; z,y with alphaD; x-sums incremental) ----
#pragma unroll
        for (int c = 0; c < 4; c++) {
            x[c] += alphaP * dx[c];
            s[c] += alphaP * ds[c];
            z[c] += alphaD * dz[c];
            s_ct[c] += alphaP * ds_ct[c];
            z_ct[c] += alphaD * dz_ct[c];
            cs[c] += alphaP * csdx[c];
        }
        yv += alphaD * dy;
        s_rt += alphaP * ds_rt;
        z_rt += alphaD * dz_rt;
        rsx += alphaP * rsdx;
        ra  += alphaP * sumdx;
    }

    // ---- emd = p.x + |sum w1 - sum w2| ----
    double e = sum16d(cross4d(px[0]*x[0] + px[1]*x[1] + px[2]*x[2] + px[3]*x[3]));
    if (l == 0) out[b] = (float)(e + sE);
}

extern "C" void kernel_launch(void* const* d_in, const int* in_sizes, int n_in,
                              void* d_out, int out_size, void* d_ws, size_t ws_size,
                              hipStream_t stream) {
    const float* jets1 = (const float*)d_in[0];
    const float* jets2 = (const float*)d_in[1];
    float* out = (float*)d_out;
    int B = in_sizes[0] / 48;   // 32
    emd_ip_kernel<<<dim3(B), dim3(64), 0, stream>>>(jets1, jets2, out);
}

// Round 5
// 112.647 us; speedup vs baseline: 1.0320x; 1.0027x over previous
//
#include <hip/hip_runtime.h>
#include <math.h>

#define L2C  1e-4
#define SIGC 0.1
#define NITER 20

// permlane swaps via builtins (R2-proven green; R0/R1 asm variants NaN'd:
// regalloc coalescing + unhandled VALU->permlane hazard inside asm blobs).
#if defined(__has_builtin)
#  if __has_builtin(__builtin_amdgcn_permlane16_swap) && __has_builtin(__builtin_amdgcn_permlane32_swap)
#    define HAVE_PLSWAP 1
#  endif
#  if __has_builtin(__builtin_amdgcn_rcp)
#    define HAVE_RCP64 1
#  endif
#endif
#ifndef HAVE_PLSWAP
#  define HAVE_PLSWAP 0
#endif
#ifndef HAVE_RCP64
#  define HAVE_RCP64 0
#endif

// ---- cross-lane helpers ----------------------------------------------------
__device__ __forceinline__ double rld(double v, int lane) {
    union { double d; int i[2]; } u, r; u.d = v;
    r.i[0] = __builtin_amdgcn_readlane(u.i[0], lane);
    r.i[1] = __builtin_amdgcn_readlane(u.i[1], lane);
    return r.d;
}
template <int CTRL>
__device__ __forceinline__ double dppd(double v) {
    union { double d; int i[2]; } u, r; u.d = v;
    r.i[0] = __builtin_amdgcn_update_dpp(0, u.i[0], CTRL, 0xF, 0xF, true);
    r.i[1] = __builtin_amdgcn_update_dpp(0, u.i[1], CTRL, 0xF, 0xF, true);
    return r.d;
}
// sum across each 16-lane DPP row (all lanes get the row total)
__device__ __forceinline__ double sum16d(double v) {
    v += dppd<0xB1>(v); v += dppd<0x4E>(v); v += dppd<0x124>(v); v += dppd<0x128>(v);
    return v;
}
template <int CTRL>
__device__ __forceinline__ float dppf(float v) {
    return __int_as_float(__builtin_amdgcn_update_dpp(0, __float_as_int(v), CTRL, 0xF, 0xF, true));
}
__device__ __forceinline__ float min16f(float v) {
    v = fminf(v, dppf<0xB1>(v)); v = fminf(v, dppf<0x4E>(v));
    v = fminf(v, dppf<0x124>(v)); v = fminf(v, dppf<0x128>(v));
    return v;
}
__device__ __forceinline__ double mkd(unsigned lo, unsigned hi) {
    union { unsigned u[2]; double d; } r; r.u[0] = lo; r.u[1] = hi; return r.d;
}
__device__ __forceinline__ void dsplit(double v, unsigned &lo, unsigned &hi) {
    union { double d; unsigned u[2]; } x; x.d = v; lo = x.u[0]; hi = x.u[1];
}
// combine the 4 16-lane rows (sum over {q, q+16, q+32, q+48}); order-independent.
__device__ __forceinline__ double cross4d(double v) {
#if HAVE_PLSWAP
    unsigned lo, hi; dsplit(v, lo, hi);
    auto rl = __builtin_amdgcn_permlane16_swap(lo, lo, false, false);
    auto rh = __builtin_amdgcn_permlane16_swap(hi, hi, false, false);
    v = mkd(rl[0], rh[0]) + mkd(rl[1], rh[1]);
    dsplit(v, lo, hi);
    auto sl = __builtin_amdgcn_permlane32_swap(lo, lo, false, false);
    auto sh = __builtin_amdgcn_permlane32_swap(hi, hi, false, false);
    return mkd(sl[0], sh[0]) + mkd(sl[1], sh[1]);
#else
    v += __shfl_xor(v, 16, 64); v += __shfl_xor(v, 32, 64); return v;
#endif
}
__device__ __forceinline__ float cross4minf(float v) {
#if HAVE_PLSWAP
    auto a = __builtin_amdgcn_permlane16_swap(__float_as_uint(v), __float_as_uint(v), false, false);
    v = fminf(__uint_as_float(a[0]), __uint_as_float(a[1]));
    auto b = __builtin_amdgcn_permlane32_swap(__float_as_uint(v), __float_as_uint(v), false, false);
    return fminf(__uint_as_float(b[0]), __uint_as_float(b[1]));
#else
    v = fminf(v, __shfl_xor(v, 16, 64)); v = fminf(v, __shfl_xor(v, 32, 64)); return v;
#endif
}
// fast fp64 reciprocal (v_rcp_f64 seed + one Newton), ~1e-14 rel err.
__device__ __forceinline__ double drcp(double d) {
#if HAVE_RCP64
    double x = __builtin_amdgcn_rcp(d);
#else
    double x = (double)__builtin_amdgcn_rcpf((float)d);
#endif
    x = x * (2.0 - d * x);
    return x;
}
__device__ __forceinline__ float frcpf(float x) { return __builtin_amdgcn_rcpf(x); }

// One 64-lane wave per batch element. Lane l: q=l&15 (flow row q), r=l>>4;
// owns cells (q, 4c+r), c=0..3. fp64 state, fixed sigma=0.1, separate
// primal/dual step lengths, exit at mu<1e-4 (the harness-proven numerics).
// Profile model (R3): ~7560 cy/iter wall vs ~3600 issued -> half exposed
// serial latency (LDLT ladder, tri-solves, Sst LDS round trip). R4 attacks
// the spine: fwd solve FUSED into the ladder (rides drcp latency shadows,
// bitwise-identical); Sr gathered by permlane butterfly (kills the Sst
// round trip; ISA-derived convention ret0=x[l&~m], probe-guarded w/ LDS
// fallback); split solves carry one rhs per wave-half in a single register
// (ysol); reciprocal pairings (one drcp -> 1/s and 1/(L2C+z/s); s*z products
// reused); gpR sum fused (csR eliminated); rsdx from urow/vrow.
__global__ __launch_bounds__(64, 1) void emd_ip_kernel(const float* __restrict__ jets1,
                                                       const float* __restrict__ jets2,
                                                       float* __restrict__ out) {
    const int l = threadIdx.x;
    const int b = blockIdx.x;
    const int q = l & 15;
    const int r = l >> 4;

    __shared__ double invDl[16 * 17];      // C[i][j] at i*17+j (stride-17: conflict-free)
    __shared__ double Sst[16 * 17];        // Schur staging (fallback path only)
    __shared__ double Lst[16 * 17];        // Lst[a*17+b] = L[b][a] (unit-diag L)
    __shared__ double Gst[2][16];          // rhs staging: [0]=R, [1]=I

    const float* p1 = jets1 + b * 48;
    const float* p2 = jets2 + b * 48;

    double ax = (double)p1[3 * q], ay = (double)p1[3 * q + 1];
    double px[4];
#pragma unroll
    for (int c = 0; c < 4; c++) {
        int j = 4 * c + r;
        double d0 = ((double)p2[3 * j]     - ax) + 1e-12;
        double d1 = ((double)p2[3 * j + 1] - ay) + 1e-12;
        px[c] = sqrt(d0 * d0 + d1 * d1);
    }
    double h_rt = (double)p1[3 * q + 2];
    double h_ct[4];
#pragma unroll
    for (int c = 0; c < 4; c++) h_ct[c] = (double)p2[3 * (4 * c + r) + 2];

    double sw1 = sum16d(h_rt);
    double sw2 = sum16d((double)p2[3 * q + 2]);
    const double sB = fmin(sw1, sw2);
    const double sE = fabs(sw1 - sw2);

    // probe the permlane-swap output convention once (ISA-derived expectation:
    // ret0 = x[l&~m], ret1 = x[l|m]); fallback to LDS gather if it ever flips.
#if HAVE_PLSWAP
    auto pr16 = __builtin_amdgcn_permlane16_swap((unsigned)l, (unsigned)l, false, false);
    auto pr32 = __builtin_amdgcn_permlane32_swap((unsigned)l, (unsigned)l, false, false);
    const bool convOK = (__builtin_amdgcn_readfirstlane((int)pr16[0]) == 0) &&
                        (__builtin_amdgcn_readfirstlane((int)pr16[1]) == 16) &&
                        (__builtin_amdgcn_readfirstlane((int)pr32[0]) == 0) &&
                        (__builtin_amdgcn_readfirstlane((int)pr32[1]) == 32);
#else
    const bool convOK = false;
#endif

    double x[4] = {0, 0, 0, 0}, s[4] = {1, 1, 1, 1}, z[4] = {1, 1, 1, 1};
    double yv = 0.0;
    double s_rt = 1.0, z_rt = 1.0;
    double s_ct[4] = {1, 1, 1, 1}, z_ct[4] = {1, 1, 1, 1};
    // incrementally-maintained sums of x (x starts at 0)
    double rsx = 0.0;                      // row-q sum of x
    double cs[4] = {0, 0, 0, 0};           // col 4c+r sums of x
    double ra = -sB;                       // sum(x) - sB

    for (int it = 0; it < NITER; ++it) {
        // ---- paired reciprocals + invDl stores (mu-independent; overlap the
        //      mu butterfly and bury the invDl lgkm latency) ----
        double prt = s_rt * z_rt;
        double irt = drcp(prt);
        double is_rt = z_rt * irt, iz_rt = s_rt * irt;
        double srz = (s_rt * s_rt) * irt;      // s_rt/z_rt
        double pct[4], is_ct[4], iz_ct[4];
#pragma unroll
        for (int c = 0; c < 4; c++) {
            pct[c] = s_ct[c] * z_ct[c];
            double ict = drcp(pct[c]);
            is_ct[c] = z_ct[c] * ict;
            iz_ct[c] = s_ct[c] * ict;
        }
        double szc[4], is_[4], iD[4];
#pragma unroll
        for (int c = 0; c < 4; c++) {
            szc[c] = s[c] * z[c];
            double tc = fma(L2C, s[c], z[c]);      // L2C*s + z
            double ip = drcp(s[c] * tc);
            is_[c] = tc * ip;                      // 1/s
            iD[c]  = (s[c] * s[c]) * ip;           // 1/(L2C + z/s)
            invDl[q * 17 + 4 * c + r] = iD[c];
        }

        // ---- mu = mean(s*z) over 288 (redundant copies scaled) ----
        double mub = szc[0] + szc[1] + szc[2] + szc[3]
                   + 0.25 * prt
                   + 0.0625 * (pct[0] + pct[1] + pct[2] + pct[3]);
        double mu = sum16d(cross4d(mub)) * (1.0 / 288.0);
        if (!(mu >= 1e-4)) break;   // gap ~ 288*mu ~ 2.9e-2 < 9.6e-2/2; catches NaN
        double sgmu = SIGC * mu;

        // ---- tail residuals (lane-local; rsx/cs maintained incrementally) ----
        double rp_rt = rsx + s_rt - h_rt;
        double rs_rt = prt - sgmu;
        double tt_rt = (z_rt * (rsx - h_rt) + sgmu) * is_rt;
        double rp_ct[4], rs_ct[4], tt_ct[4];
#pragma unroll
        for (int c = 0; c < 4; c++) {
            rp_ct[c] = cs[c] + s_ct[c] - h_ct[c];
            rs_ct[c] = pct[c] - sgmu;
            tt_ct[c] = (z_ct[c] * (cs[c] - h_ct[c]) + sgmu) * is_ct[c];
        }

        // ---- cell residuals ----
        double rp[4], rs[4], r1[4], rD1[4];
#pragma unroll
        for (int c = 0; c < 4; c++) {
            double rx = L2C * x[c] + px[c] + (-z[c] + z_rt + z_ct[c]) + yv;
            rp[c] = s[c] - x[c];
            rs[c] = szc[c] - sgmu;
            double tk = (sgmu - z[c] * x[c]) * is_[c];   // (z*rp - rs)/s
            r1[c] = rx - tk + tt_rt + tt_ct[c];
            rD1[c] = r1[c] * iD[c];
        }

        // ---- sums of invD, rD1 ----
        double rsI = cross4d(iD[0] + iD[1] + iD[2] + iD[3]);
        double rsR = cross4d(rD1[0] + rD1[1] + rD1[2] + rD1[3]);
        double csI[4];
#pragma unroll
        for (int c = 0; c < 4; c++) csI[c] = sum16d(iD[c]);

        double ar = drcp(srz + rsI);   // 1/A_q
        double aR = ar * rsR;
        double aI = ar * rsI;

        // ---- rhs gp[j] = g_c[j] - sum_i aX_i*C[i][j]; gpR fused (linearity
        //      of sum16d: csR - sum(aR*iD) == sum(rD1 - aR*iD)) ----
        double bb[4];
#pragma unroll
        for (int c = 0; c < 4; c++) {
            double gpR = sum16d(rD1[c] - aR * iD[c]);
            double gpI = csI[c] - sum16d(aI * iD[c]);
            bb[c] = s_ct[c] * iz_ct[c] + csI[c];
            if (q == 4 * c + r) { Gst[0][q] = gpR; Gst[1][q] = gpI; }  // stage
        }

        // ---- Schur S[q][4c+r] = diag - sum_t ar_t C[t][q] C[t][4c+r] ----
        // split accumulators: fp64 fma chain depth 16 -> 8 (+1 add)
        double accA[4] = {0, 0, 0, 0}, accB[4] = {0, 0, 0, 0};
#pragma unroll
        for (int t = 0; t < 8; t++) {
            double wA = rld(ar, t) * invDl[t * 17 + q];
            double wB = rld(ar, t + 8) * invDl[(t + 8) * 17 + q];
#pragma unroll
            for (int c = 0; c < 4; c++) {
                accA[c] += wA * invDl[t * 17 + 4 * c + r];
                accB[c] += wB * invDl[(t + 8) * 17 + 4 * c + r];
            }
        }
        double Sv[4];
#pragma unroll
        for (int c = 0; c < 4; c++)
            Sv[c] = ((q == 4 * c + r) ? bb[c] : 0.0) - (accA[c] + accB[c]);

        // ---- gather row q of S into registers ----
        // fast path: permlane butterfly resolves both r-bits to compile-time
        // slots (~40 VALU b32 swaps, no LDS round trip on the spine).
        // step1 swap16: ret0 = col 4c+(r&~1), ret1 = col 4c+(r|1);
        // step2 swap32 on each: +-(r bit1) -> cols 4c+{0,2} / 4c+{1,3}.
        double Sr[16];
#if HAVE_PLSWAP
        if (convOK) {
#pragma unroll
            for (int c = 0; c < 4; c++) {
                unsigned xl, xh; dsplit(Sv[c], xl, xh);
                auto sl = __builtin_amdgcn_permlane16_swap(xl, xl, false, false);
                auto sh = __builtin_amdgcn_permlane16_swap(xh, xh, false, false);
                auto e = __builtin_amdgcn_permlane32_swap(sl[0], sl[0], false, false);
                auto f = __builtin_amdgcn_permlane32_swap(sh[0], sh[0], false, false);
                auto g = __builtin_amdgcn_permlane32_swap(sl[1], sl[1], false, false);
                auto h = __builtin_amdgcn_permlane32_swap(sh[1], sh[1], false, false);
                Sr[4 * c + 0] = mkd(e[0], f[0]);
                Sr[4 * c + 2] = mkd(e[1], f[1]);
                Sr[4 * c + 1] = mkd(g[0], h[0]);
                Sr[4 * c + 3] = mkd(g[1], h[1]);
            }
        } else
#endif
        {
#pragma unroll
            for (int c = 0; c < 4; c++) Sst[q * 17 + 4 * c + r] = Sv[c];
#pragma unroll
            for (int j2 = 0; j2 < 16; j2++) Sr[j2] = Sst[q * 17 + j2];
        }

        // ---- pivot floors precomputed (off the serial pivot chain) ----
        double flo[16];
#pragma unroll
        for (int kk = 0; kk < 16; kk++)
            flo[kk] = fmax(1e-12 * fabs(rld(Sr[kk], kk)), 1e-280);

        // ---- rhs read: one register per lane; r<2 carries R, r>=2 carries I ----
        double ysol = Gst[r >> 1][q];

        // ---- 16x16 LDLT (unit-diag L) + FUSED forward solve ----
        // fwd fma rides the ladder's drcp latency shadow: at step kk, Lc IS
        // L[q][kk] and lane kk's (kk+32's) ysol is final. pcand pivot bypass
        // keeps the next pivot readlane off the rank-1 update.
        double invdv = 0.0;   // 1/d_q (own pivot) for the D-divide
        double pcand = 0.0;
#pragma unroll
        for (int kk = 0; kk < 16; kk++) {
            double praw = (kk == 0) ? rld(Sr[0], 0) : rld(pcand, kk);
            double dkk = fmax(praw, flo[kk]);
            double inv = drcp(dkk);
            invdv = (q == kk) ? inv : invdv;
            double Lc = Sr[kk] * inv;      // L[q][kk] (unit diag; valid q>=kk)
            if (l < 16) Lst[kk * 17 + l] = Lc;
            if (kk < 15) pcand = Sr[kk + 1] - Sr[kk] * Lc;   // lane-local next-pivot
            // fused forward solve (split halves, one fma)
            double t1 = rld(ysol, kk);
            double t2 = rld(ysol, kk + 32);
            double tt = (r < 2) ? t1 : t2;
            if (q > kk) ysol -= Lc * tt;
#pragma unroll
            for (int jj = kk + 1; jj < 16; jj++)
                Sr[jj] -= Sr[kk] * rld(Lc, jj);   // -= (L[q][kk]*d)*L[jj][kk]
            Sr[kk] = Lc;                   // keep L column (unused now, cheap)
        }

        // ---- D-divide (lane-local) ----
        ysol *= invdv;

        // ---- gather L^T row from LDS (issued before the bwd chain starts) ----
        double LTr[16];
#pragma unroll
        for (int kk = 0; kk < 16; kk++) LTr[kk] = Lst[q * 17 + kk];  // L[kk][q]

        // ---- backward solve L^T qc = v (split halves) ----
#pragma unroll
        for (int kk = 15; kk >= 0; kk--) {
            double t1 = rld(ysol, kk);
            double t2 = rld(ysol, kk + 32);
            double tt = (r < 2) ? t1 : t2;
            if (q < kk) ysol -= LTr[kk] * tt;
        }
        // lanes 0..15: ysol = qcR[q]; lanes 32..47: ysol = qcI[q]

        // ---- gather qc per own columns (sourced from the valid halves) ----
        double qc1c[4], qcvc[4];
#pragma unroll
        for (int c = 0; c < 4; c++) {
            qc1c[c] = __shfl(ysol, 4 * c + r, 64);
            qcvc[c] = __shfl(ysol, 32 + 4 * c + r, 64);
        }

        // ---- qr = ar*(g_r - sum_j C[q][j] qc_j) (cross4 reduction) ----
        double pr1 = iD[0]*qc1c[0] + iD[1]*qc1c[1] + iD[2]*qc1c[2] + iD[3]*qc1c[3];
        double prv = iD[0]*qcvc[0] + iD[1]*qcvc[1] + iD[2]*qcvc[2] + iD[3]*qcvc[3];
        double qr1 = ar * (rsR - cross4d(pr1));
        double qrv = ar * (rsI - cross4d(prv));

        // ---- u = H^{-1} r1, v = H^{-1} 1 ----
        double u[4], v[4];
#pragma unroll
        for (int c = 0; c < 4; c++) {
            u[c] = (r1[c] - qr1 - qc1c[c]) * iD[c];
            v[c] = (1.0  - qrv - qcvc[c]) * iD[c];
        }
        double urow = cross4d(u[0] + u[1] + u[2] + u[3]);
        double vrow = cross4d(v[0] + v[1] + v[2] + v[3]);
        double usum = sum16d(urow);
        double vsum = sum16d(vrow);
        double dy = (ra - usum) * drcp(vsum);

        // ---- dx + sums (rsdx reuses urow/vrow) ----
        double dx[4];
#pragma unroll
        for (int c = 0; c < 4; c++) dx[c] = -u[c] - v[c] * dy;
        double rsdx = -urow - vrow * dy;
        double csdx[4];
#pragma unroll
        for (int c = 0; c < 4; c++) csdx[c] = sum16d(dx[c]);
        double sumdx = -usum - vsum * dy;   // sum over all cells of dx (exact identity)

        // ---- ds, dz; SEPARATE primal/dual ratio tests (fp32, 0.99 margin) ----
        float amP = 1e30f, amD = 1e30f;
        double ds[4], dz[4];
#pragma unroll
        for (int c = 0; c < 4; c++) {
            ds[c] = dx[c] - rp[c];
            dz[c] = -(rs[c] + z[c] * ds[c]) * is_[c];
            if (ds[c] < 0.0) amP = fminf(amP, (float)s[c] * frcpf((float)(-ds[c])));
            if (dz[c] < 0.0) amD = fminf(amD, (float)z[c] * frcpf((float)(-dz[c])));
        }
        double ds_rt = -rp_rt - rsdx;
        double dz_rt = -(rs_rt + z_rt * ds_rt) * is_rt;
        if (ds_rt < 0.0) amP = fminf(amP, (float)s_rt * frcpf((float)(-ds_rt)));
        if (dz_rt < 0.0) amD = fminf(amD, (float)z_rt * frcpf((float)(-dz_rt)));
        double ds_ct[4], dz_ct[4];
#pragma unroll
        for (int c = 0; c < 4; c++) {
            ds_ct[c] = -rp_ct[c] - csdx[c];
            dz_ct[c] = -(rs_ct[c] + z_ct[c] * ds_ct[c]) * is_ct[c];
            if (ds_ct[c] < 0.0) amP = fminf(amP, (float)s_ct[c] * frcpf((float)(-ds_ct[c])));
            if (dz_ct[c] < 0.0) amD = fminf(amD, (float)z_ct[c] * frcpf((float)(-dz_ct[c])));
        }
        float aPf = min16f(cross4minf(amP));
        float aDf = min16f(cross4minf(amD));
        double alphaP = 0.99 * fmin(1.0, (double)aPf);
        double alphaD = 0.99 * fmin(1.0, (double)aDf);
        bool good = ((dy - dy) == 0.0);   // freeze on garbage direction
        alphaP = good ? alphaP : 0.0;
        alphaD = good ? alphaD : 0.0;

        // ---- step (x,s with alphaP; z,y with alphaD; x-sums incremental) ----
#pragma unroll
        for (int c = 0; c < 4; c++) {
            x[c] += alphaP * dx[c];
            s[c] += alphaP * ds[c];
            z[c] += alphaD * dz[c];
            s_ct[c] += alphaP * ds_ct[c];
            z_ct[c] += alphaD * dz_ct[c];
            cs[c] += alphaP * csdx[c];
        }
        yv += alphaD * dy;
        s_rt += alphaP * ds_rt;
        z_rt += alphaD * dz_rt;
        rsx += alphaP * rsdx;
        ra  += alphaP * sumdx;
    }

    // ---- emd = p.x + |sum w1 - sum w2| ----
    double e = sum16d(cross4d(px[0]*x[0] + px[1]*x[1] + px[2]*x[2] + px[3]*x[3]));
    if (l == 0) out[b] = (float)(e + sE);
}

extern "C" void kernel_launch(void* const* d_in, const int* in_sizes, int n_in,
                              void* d_out, int out_size, void* d_ws, size_t ws_size,
                              hipStream_t stream) {
    const float* jets1 = (const float*)d_in[0];
    const float* jets2 = (const float*)d_in[1];
    float* out = (float*)d_out;
    int B = in_sizes[0] / 48;   // 32
    emd_ip_kernel<<<dim3(B), dim3(64), 0, stream>>>(jets1, jets2, out);
}